// Round 4
// baseline (178.765 us; speedup 1.0000x reference)
//
#include <hip/hip_runtime.h>
#include <hip/hip_bf16.h>

#define NB 8192
#define ND 128

static constexpr float F_ALPHA  = 2.0f;
static constexpr float F_BETA   = 50.0f;
static constexpr float F_BASE   = 0.5f;
static constexpr float F_MARGIN = 0.1f;
static constexpr float LOG2E    = 1.4426950408889634f;
// exp(-A*(s-B)) = exp2(s*C1P + C0P); exp(B*(s-B)) = exp2(s*C1N + C0N)
static constexpr float C1P = -F_ALPHA * LOG2E, C0P =  F_ALPHA * F_BASE * LOG2E;
static constexpr float C1N =  F_BETA  * LOG2E, C0N = -F_BETA  * F_BASE * LOG2E;

typedef __attribute__((ext_vector_type(8))) short short8;
typedef __attribute__((ext_vector_type(4))) float f32x4;

// monotone float<->uint encoding for atomic min/max
__device__ __forceinline__ unsigned fenc(float f) {
  unsigned u = __float_as_uint(f);
  return (u & 0x80000000u) ? ~u : (u | 0x80000000u);
}
__device__ __forceinline__ float fdec(unsigned k) {
  unsigned u = (k & 0x80000000u) ? (k & 0x7FFFFFFFu) : ~k;
  return __uint_as_float(u);
}

// fp32 -> bf16 convert + stat-array init + label histogram
__global__ void k_convert(const float4* __restrict__ in, ushort4* __restrict__ out,
                          const int* __restrict__ lab,
                          unsigned* __restrict__ pmKey, unsigned* __restrict__ nmKey,
                          float* __restrict__ pSum, float* __restrict__ nSum,
                          int* __restrict__ cnt) {
  int i = blockIdx.x * 256 + threadIdx.x;
  float4 v = in[i];
  __hip_bfloat16 a = __float2bfloat16(v.x), b = __float2bfloat16(v.y),
                 c = __float2bfloat16(v.z), d = __float2bfloat16(v.w);
  ushort4 o;
  o.x = *(unsigned short*)&a; o.y = *(unsigned short*)&b;
  o.z = *(unsigned short*)&c; o.w = *(unsigned short*)&d;
  out[i] = o;
  if (i < NB) {
    pmKey[i] = 0xFFFFFFFFu;   // atomic-min identity
    nmKey[i] = 0u;            // atomic-max identity
    pSum[i]  = 0.f;
    nSum[i]  = 0.f;
    atomicAdd(&cnt[lab[i]], 1);
  }
}

// LDS-free, barrier-free. Each WAVE owns 32 rows x 512 cols: A-fragments in
// registers (from global, L2-hit), B-fragments read per 64-col tile directly
// from L2. Self (diagonal) counts as a positive for pos_min (self-sim ~ 1.0
// >= all cross sims, so min unaffected when a true positive exists); pair
// existence comes from the label histogram; pass 0 captures the MFMA-exact
// self-sim, and k_final subtracts self's conditional hard-pos term.
template<int PASS>
__global__ __launch_bounds__(256, 3)
void k_simpass(const __hip_bfloat16* __restrict__ E,
               const int* __restrict__ lab,
               unsigned* __restrict__ pmKey,
               unsigned* __restrict__ nmKey,
               float* __restrict__ pSum,
               float* __restrict__ nSum,
               float* __restrict__ selfSim)
{
  const int t    = threadIdx.x;
  const int lane = t & 63, wid = t >> 6;
  const int q    = lane >> 4, r15 = lane & 15;
  const int rBase  = blockIdx.y * 128 + wid * 32;
  const int cBase0 = blockIdx.x * 512;
  const char* Eb = (const char*)E;

  // A fragments: 32 rows x 128 K -> 8 x short8 = 32 VGPR (L2-resident reads)
  short8 afr[4][2];   // [kk][mi]
#pragma unroll
  for (int mi = 0; mi < 2; ++mi) {
    const char* pa = Eb + (size_t)(rBase + mi * 16 + r15) * 256 + q * 16;
#pragma unroll
    for (int kk = 0; kk < 4; ++kk)
      afr[kk][mi] = *(const short8*)(pa + kk * 64);
  }

  // per-row data for this lane's 8 C-rows (row = mi*16 + q*4 + rg)
  int lrr[8]; float pmr[8], nmr[8];
#pragma unroll
  for (int mi = 0; mi < 2; ++mi)
#pragma unroll
    for (int rg = 0; rg < 4; ++rg) {
      int r = rBase + mi * 16 + q * 4 + rg;
      lrr[mi * 4 + rg] = lab[r];
      if (PASS == 1) {
        pmr[mi * 4 + rg] = fdec(pmKey[r]);
        nmr[mi * 4 + rg] = fdec(nmKey[r]);
      }
    }

  float st1[8], st2[8];
#pragma unroll
  for (int i = 0; i < 8; ++i) {
    st1[i] = (PASS == 0) ?  __builtin_inff() : 0.f;
    st2[i] = (PASS == 0) ? -__builtin_inff() : 0.f;
  }

  for (int ct = 0; ct < 8; ++ct) {
    const int cBase = cBase0 + ct * 64;

    int cl[4];
#pragma unroll
    for (int ni = 0; ni < 4; ++ni) cl[ni] = lab[cBase + ni * 16 + r15];

    f32x4 acc[2][4];
#pragma unroll
    for (int mi = 0; mi < 2; ++mi)
#pragma unroll
      for (int ni = 0; ni < 4; ++ni)
        acc[mi][ni] = (f32x4){0.f, 0.f, 0.f, 0.f};

#pragma unroll
    for (int kk = 0; kk < 4; ++kk) {
      short8 bfr[4];
#pragma unroll
      for (int ni = 0; ni < 4; ++ni)
        bfr[ni] = *(const short8*)(Eb + (size_t)(cBase + ni * 16 + r15) * 256 +
                                   kk * 64 + q * 16);
#pragma unroll
      for (int mi = 0; mi < 2; ++mi)
#pragma unroll
        for (int ni = 0; ni < 4; ++ni)
          acc[mi][ni] = __builtin_amdgcn_mfma_f32_16x16x32_bf16(
              afr[kk][mi], bfr[ni], acc[mi][ni], 0, 0, 0);
    }

    // fold (no diagonal compare: self acts as a positive)
#pragma unroll
    for (int mi = 0; mi < 2; ++mi)
#pragma unroll
      for (int rg = 0; rg < 4; ++rg) {
        const int idx = mi * 4 + rg;
        const int lr  = lrr[idx];
#pragma unroll
        for (int ni = 0; ni < 4; ++ni) {
          float s = acc[mi][ni][rg];
          bool same = (lr == cl[ni]);
          if (PASS == 0) {
            st1[idx] = fminf(st1[idx], same ? s :  __builtin_inff());
            st2[idx] = fmaxf(st2[idx], same ? -__builtin_inff() : s);
          } else {
            bool hp = same  && (s - F_MARGIN < nmr[idx]);
            bool hn = !same && (s + F_MARGIN > pmr[idx]);
            float e = __builtin_amdgcn_exp2f(
                fmaf(s, same ? C1P : C1N, same ? C0P : C0N));
            st1[idx] += hp ? e : 0.f;
            st2[idx] += hn ? e : 0.f;
          }
        }
      }

    // capture MFMA-exact diagonal (uniform branch; one tile per 16 waves)
    if (PASS == 0 && (unsigned)(rBase - cBase) < 64u) {
#pragma unroll
      for (int mi = 0; mi < 2; ++mi)
#pragma unroll
        for (int ni = 0; ni < 4; ++ni)
#pragma unroll
          for (int rg = 0; rg < 4; ++rg) {
            int r = rBase + mi * 16 + q * 4 + rg;
            if (cBase + ni * 16 + r15 == r) selfSim[r] = acc[mi][ni][rg];
          }
    }
  }

  // epilogue: reduce over the 16-lane col groups, then one atomic per row
#pragma unroll
  for (int mi = 0; mi < 2; ++mi)
#pragma unroll
    for (int rg = 0; rg < 4; ++rg) {
      const int idx = mi * 4 + rg;
      const int r   = rBase + mi * 16 + q * 4 + rg;
      float v1 = st1[idx], v2 = st2[idx];
      if (PASS == 0) {
#pragma unroll
        for (int d = 1; d < 16; d <<= 1) {
          v1 = fminf(v1, __shfl_xor(v1, d));
          v2 = fmaxf(v2, __shfl_xor(v2, d));
        }
        if (r15 == 0) {
          atomicMin(&pmKey[r], fenc(v1));
          atomicMax(&nmKey[r], fenc(v2));
        }
      } else {
#pragma unroll
        for (int d = 1; d < 16; d <<= 1) {
          v1 += __shfl_xor(v1, d);
          v2 += __shfl_xor(v2, d);
        }
        if (r15 == 0) {
          if (v1 != 0.f) atomicAdd(&pSum[r], v1);
          if (v2 != 0.f) atomicAdd(&nSum[r], v2);
        }
      }
    }
}

__global__ void k_final(const unsigned* __restrict__ pmKey,
                        const unsigned* __restrict__ nmKey,
                        const float* __restrict__ pSum,
                        const float* __restrict__ nSum,
                        const float* __restrict__ selfSim,
                        const int* __restrict__ lab,
                        const int* __restrict__ cnt,
                        float* __restrict__ out)
{
  const int t = threadIdx.x;
  float ls = 0.f, nv = 0.f;
  for (int r = t; r < NB; r += 1024) {
    int c = cnt[lab[r]];
    unsigned nk = nmKey[r];
    bool pe = (c > 1);                 // a true positive pair exists
    bool ne = (c < NB) && (nk > 0x007FFFFFu);
    if (pe && ne) {
      float pm = fdec(pmKey[r]), nm = fdec(nk);
      if (pm - F_MARGIN < nm) {        // hard_pos.any <=> hard_neg.any
        float ss = selfSim[r];
        float psub = (ss - F_MARGIN < nm)
                       ? __builtin_amdgcn_exp2f(fmaf(ss, C1P, C0P)) : 0.f;
        float ps = fmaxf(pSum[r] - psub, 0.f);
        ls += log1pf(ps) * (1.0f / F_ALPHA) + log1pf(nSum[r]) * (1.0f / F_BETA);
        nv += 1.f;
      }
    }
  }
#pragma unroll
  for (int d = 1; d < 64; d <<= 1) {
    ls += __shfl_xor(ls, d);
    nv += __shfl_xor(nv, d);
  }
  __shared__ float sL[16], sC[16];
  if ((t & 63) == 0) { sL[t >> 6] = ls; sC[t >> 6] = nv; }
  __syncthreads();
  if (t == 0) {
    float a = 0.f, c = 0.f;
#pragma unroll
    for (int w = 0; w < 16; ++w) { a += sL[w]; c += sC[w]; }
    out[0] = a / fmaxf(c, 1.f);
  }
}

extern "C" void kernel_launch(void* const* d_in, const int* in_sizes, int n_in,
                              void* d_out, int out_size, void* d_ws, size_t ws_size,
                              hipStream_t stream)
{
  const float* emb = (const float*)d_in[0];
  const int*   lab = (const int*)d_in[1];
  float* out = (float*)d_out;

  char* ws = (char*)d_ws;
  __hip_bfloat16* ebf = (__hip_bfloat16*)ws;                    // 2 MB
  unsigned* pmKey   = (unsigned*)(ws + 2097152);                // 32 KB
  unsigned* nmKey   = (unsigned*)(ws + 2097152 + 32768);        // 32 KB
  float*    pSum    = (float*)(ws + 2097152 + 65536);           // 32 KB
  float*    nSum    = (float*)(ws + 2097152 + 98304);           // 32 KB
  float*    selfSim = (float*)(ws + 2097152 + 131072);          // 32 KB
  int*      cnt     = (int*)(ws + 2097152 + 163840);            // 2 KB

  hipMemsetAsync(cnt, 0, 512 * sizeof(int), stream);
  k_convert<<<NB * ND / (256 * 4), 256, 0, stream>>>(
      (const float4*)emb, (ushort4*)ebf, lab, pmKey, nmKey, pSum, nSum, cnt);

  dim3 grid(16, 64);   // 16 col-chunks x 64 row-groups; 4 indep waves/block
  k_simpass<0><<<grid, 256, 0, stream>>>(ebf, lab, pmKey, nmKey, pSum, nSum, selfSim);
  k_simpass<1><<<grid, 256, 0, stream>>>(ebf, lab, pmKey, nmKey, pSum, nSum, selfSim);
  k_final<<<1, 1024, 0, stream>>>(pmKey, nmKey, pSum, nSum, selfSim, lab, cnt, out);
}

// Round 5
// 116.855 us; speedup vs baseline: 1.5298x; 1.5298x over previous
//
#include <hip/hip_runtime.h>
#include <hip/hip_bf16.h>

#define NB 8192
#define ND 128

static constexpr float F_ALPHA  = 2.0f;
static constexpr float F_BETA   = 50.0f;
static constexpr float F_BASE   = 0.5f;
static constexpr float F_MARGIN = 0.1f;
static constexpr float LOG2E    = 1.4426950408889634f;
// exp(-A*(s-B)) = exp2(s*C1P + C0P); exp(B*(s-B)) = exp2(s*C1N + C0N)
static constexpr float C1P = -F_ALPHA * LOG2E, C0P =  F_ALPHA * F_BASE * LOG2E;
static constexpr float C1N =  F_BETA  * LOG2E, C0N = -F_BETA  * F_BASE * LOG2E;

typedef __attribute__((ext_vector_type(8))) short short8;
typedef __attribute__((ext_vector_type(4))) float f32x4;

// monotone float<->uint encoding for atomic min/max
__device__ __forceinline__ unsigned fenc(float f) {
  unsigned u = __float_as_uint(f);
  return (u & 0x80000000u) ? ~u : (u | 0x80000000u);
}
__device__ __forceinline__ float fdec(unsigned k) {
  unsigned u = (k & 0x80000000u) ? (k & 0x7FFFFFFFu) : ~k;
  return __uint_as_float(u);
}

__device__ __forceinline__ void async16(const void* g, void* l) {
  __builtin_amdgcn_global_load_lds(
      (const __attribute__((address_space(1))) void*)g,
      (__attribute__((address_space(3))) void*)l, 16, 0, 0);
}

// fp32 -> bf16 convert + stat-array init + label histogram
__global__ void k_convert(const float4* __restrict__ in, ushort4* __restrict__ out,
                          const int* __restrict__ lab,
                          unsigned* __restrict__ pmKey, unsigned* __restrict__ nmKey,
                          float* __restrict__ pSum, float* __restrict__ nSum,
                          int* __restrict__ cnt) {
  int i = blockIdx.x * 256 + threadIdx.x;
  float4 v = in[i];
  __hip_bfloat16 a = __float2bfloat16(v.x), b = __float2bfloat16(v.y),
                 c = __float2bfloat16(v.z), d = __float2bfloat16(v.w);
  ushort4 o;
  o.x = *(unsigned short*)&a; o.y = *(unsigned short*)&b;
  o.z = *(unsigned short*)&c; o.w = *(unsigned short*)&d;
  out[i] = o;
  if (i < NB) {
    pmKey[i] = 0xFFFFFFFFu;   // atomic-min identity
    nmKey[i] = 0u;            // atomic-max identity
    pSum[i]  = 0.f;
    nSum[i]  = 0.f;
    atomicAdd(&cnt[lab[i]], 1);
  }
}

// Block = 128 rows x 256 cols. Prologue: stage the WHOLE 64 KB B-chunk +
// 256 col labels into LDS, ONE barrier. Main loop: 4 col-tiles of 64,
// barrier-free, global-free — pure ds_read + MFMA + register fold, fully
// unrolled so the compiler pipelines across tiles. A-fragments in regs.
// Diagonal: self counts as positive for pos_min (self-sim ~1.0 >= cross
// sims); pair existence from label histogram; pass 0 stores the MFMA-exact
// self-sim and k_final subtracts self's conditional hard-pos term.
template<int PASS>
__global__ __launch_bounds__(256, 2)
void k_simpass(const __hip_bfloat16* __restrict__ E,
               const int* __restrict__ lab,
               unsigned* __restrict__ pmKey,
               unsigned* __restrict__ nmKey,
               float* __restrict__ pSum,
               float* __restrict__ nSum,
               float* __restrict__ selfSim)
{
  __shared__ __align__(16) __hip_bfloat16 sB[256 * 128];  // 64 KB
  __shared__ int sLc[256];                                 // 1 KB

  const int t    = threadIdx.x;
  const int lane = t & 63, wid = t >> 6;
  const int q    = lane >> 4, r15 = lane & 15;
  const int rBase = blockIdx.y * 128 + wid * 32;
  const int cBase0 = blockIdx.x * 256;
  const char* Eb = (const char*)E;

  // ---- prologue: stage B-chunk (swizzled source -> linear LDS) ----
  const char* gB = Eb + (size_t)cBase0 * 256;
#pragma unroll
  for (int ch = 0; ch < 16; ++ch) {
    int lin = ch * 4096 + t * 16;
    int row = lin >> 8, kb = lin & 255;
    async16(gB + row * 256 + (kb ^ ((row & 7) << 4)),
            (char*)sB + ch * 4096 + wid * 1024);
  }
  sLc[t] = lab[cBase0 + t];

  // A fragments: 32 rows x 128 K -> 8 x short8 = 32 VGPR (L2-resident)
  short8 afr[4][2];   // [kk][mi]
#pragma unroll
  for (int mi = 0; mi < 2; ++mi) {
    const char* pa = Eb + (size_t)(rBase + mi * 16 + r15) * 256 + q * 16;
#pragma unroll
    for (int kk = 0; kk < 4; ++kk)
      afr[kk][mi] = *(const short8*)(pa + kk * 64);
  }

  // per-row data for this lane's 8 C-rows (row = mi*16 + q*4 + rg)
  int lrr[8]; float pmr[8], nmr[8];
#pragma unroll
  for (int mi = 0; mi < 2; ++mi)
#pragma unroll
    for (int rg = 0; rg < 4; ++rg) {
      int r = rBase + mi * 16 + q * 4 + rg;
      lrr[mi * 4 + rg] = lab[r];
      if (PASS == 1) {
        pmr[mi * 4 + rg] = fdec(pmKey[r]);
        nmr[mi * 4 + rg] = fdec(nmKey[r]);
      }
    }

  float st1[8], st2[8];
#pragma unroll
  for (int i = 0; i < 8; ++i) {
    st1[i] = (PASS == 0) ?  __builtin_inff() : 0.f;
    st2[i] = (PASS == 0) ? -__builtin_inff() : 0.f;
  }

  __syncthreads();   // B-chunk + labels resident; no barriers after this

#pragma unroll
  for (int ct = 0; ct < 4; ++ct) {
    const int cTile = cBase0 + ct * 64;

    int cl[4];
#pragma unroll
    for (int ni = 0; ni < 4; ++ni) cl[ni] = sLc[ct * 64 + ni * 16 + r15];

    f32x4 acc[2][4];
#pragma unroll
    for (int mi = 0; mi < 2; ++mi)
#pragma unroll
      for (int ni = 0; ni < 4; ++ni)
        acc[mi][ni] = (f32x4){0.f, 0.f, 0.f, 0.f};

#pragma unroll
    for (int kk = 0; kk < 4; ++kk) {
      short8 bfr[4];
#pragma unroll
      for (int ni = 0; ni < 4; ++ni) {
        int brow = ct * 64 + ni * 16 + r15;
        bfr[ni] = *(const short8*)((const char*)sB + brow * 256 +
                    ((kk * 64 + q * 16) ^ ((brow & 7) << 4)));
      }
#pragma unroll
      for (int mi = 0; mi < 2; ++mi)
#pragma unroll
        for (int ni = 0; ni < 4; ++ni)
          acc[mi][ni] = __builtin_amdgcn_mfma_f32_16x16x32_bf16(
              afr[kk][mi], bfr[ni], acc[mi][ni], 0, 0, 0);
    }

    // branchless fold (self acts as a positive; no diagonal compare)
#pragma unroll
    for (int mi = 0; mi < 2; ++mi)
#pragma unroll
      for (int rg = 0; rg < 4; ++rg) {
        const int idx = mi * 4 + rg;
        const int lr  = lrr[idx];
#pragma unroll
        for (int ni = 0; ni < 4; ++ni) {
          float s = acc[mi][ni][rg];
          bool same = (lr == cl[ni]);
          if (PASS == 0) {
            st1[idx] = fminf(st1[idx], same ? s :  __builtin_inff());
            st2[idx] = fmaxf(st2[idx], same ? -__builtin_inff() : s);
          } else {
            bool hp = same  && (s - F_MARGIN < nmr[idx]);
            bool hn = !same && (s + F_MARGIN > pmr[idx]);
            float e = __builtin_amdgcn_exp2f(
                fmaf(s, same ? C1P : C1N, same ? C0P : C0N));
            st1[idx] += hp ? e : 0.f;
            st2[idx] += hn ? e : 0.f;
          }
        }
      }

    // capture MFMA-exact diagonal (wave-uniform branch)
    if (PASS == 0 && (unsigned)(rBase - cTile) < 64u) {
#pragma unroll
      for (int mi = 0; mi < 2; ++mi)
#pragma unroll
        for (int ni = 0; ni < 4; ++ni)
#pragma unroll
          for (int rg = 0; rg < 4; ++rg) {
            int r = rBase + mi * 16 + q * 4 + rg;
            if (cTile + ni * 16 + r15 == r) selfSim[r] = acc[mi][ni][rg];
          }
    }
  }

  // epilogue: 16-lane shuffle reduce, one atomic per row (rows disjoint
  // across waves, 32 contending blocks per address)
#pragma unroll
  for (int mi = 0; mi < 2; ++mi)
#pragma unroll
    for (int rg = 0; rg < 4; ++rg) {
      const int idx = mi * 4 + rg;
      const int r   = rBase + mi * 16 + q * 4 + rg;
      float v1 = st1[idx], v2 = st2[idx];
      if (PASS == 0) {
#pragma unroll
        for (int d = 1; d < 16; d <<= 1) {
          v1 = fminf(v1, __shfl_xor(v1, d));
          v2 = fmaxf(v2, __shfl_xor(v2, d));
        }
        if (r15 == 0) {
          atomicMin(&pmKey[r], fenc(v1));
          atomicMax(&nmKey[r], fenc(v2));
        }
      } else {
#pragma unroll
        for (int d = 1; d < 16; d <<= 1) {
          v1 += __shfl_xor(v1, d);
          v2 += __shfl_xor(v2, d);
        }
        if (r15 == 0) {
          if (v1 != 0.f) atomicAdd(&pSum[r], v1);
          if (v2 != 0.f) atomicAdd(&nSum[r], v2);
        }
      }
    }
}

__global__ void k_final(const unsigned* __restrict__ pmKey,
                        const unsigned* __restrict__ nmKey,
                        const float* __restrict__ pSum,
                        const float* __restrict__ nSum,
                        const float* __restrict__ selfSim,
                        const int* __restrict__ lab,
                        const int* __restrict__ cnt,
                        float* __restrict__ out)
{
  const int t = threadIdx.x;
  float ls = 0.f, nv = 0.f;
  for (int r = t; r < NB; r += 1024) {
    int c = cnt[lab[r]];
    unsigned nk = nmKey[r];
    bool pe = (c > 1);                 // a true positive pair exists
    bool ne = (c < NB) && (nk > 0x007FFFFFu);
    if (pe && ne) {
      float pm = fdec(pmKey[r]), nm = fdec(nk);
      if (pm - F_MARGIN < nm) {        // hard_pos.any <=> hard_neg.any
        float ss = selfSim[r];
        float psub = (ss - F_MARGIN < nm)
                       ? __builtin_amdgcn_exp2f(fmaf(ss, C1P, C0P)) : 0.f;
        float ps = fmaxf(pSum[r] - psub, 0.f);
        ls += log1pf(ps) * (1.0f / F_ALPHA) + log1pf(nSum[r]) * (1.0f / F_BETA);
        nv += 1.f;
      }
    }
  }
#pragma unroll
  for (int d = 1; d < 64; d <<= 1) {
    ls += __shfl_xor(ls, d);
    nv += __shfl_xor(nv, d);
  }
  __shared__ float sL[16], sC[16];
  if ((t & 63) == 0) { sL[t >> 6] = ls; sC[t >> 6] = nv; }
  __syncthreads();
  if (t == 0) {
    float a = 0.f, c = 0.f;
#pragma unroll
    for (int w = 0; w < 16; ++w) { a += sL[w]; c += sC[w]; }
    out[0] = a / fmaxf(c, 1.f);
  }
}

extern "C" void kernel_launch(void* const* d_in, const int* in_sizes, int n_in,
                              void* d_out, int out_size, void* d_ws, size_t ws_size,
                              hipStream_t stream)
{
  const float* emb = (const float*)d_in[0];
  const int*   lab = (const int*)d_in[1];
  float* out = (float*)d_out;

  char* ws = (char*)d_ws;
  __hip_bfloat16* ebf = (__hip_bfloat16*)ws;                    // 2 MB
  unsigned* pmKey   = (unsigned*)(ws + 2097152);                // 32 KB
  unsigned* nmKey   = (unsigned*)(ws + 2097152 + 32768);        // 32 KB
  float*    pSum    = (float*)(ws + 2097152 + 65536);           // 32 KB
  float*    nSum    = (float*)(ws + 2097152 + 98304);           // 32 KB
  float*    selfSim = (float*)(ws + 2097152 + 131072);          // 32 KB
  int*      cnt     = (int*)(ws + 2097152 + 163840);            // 2 KB

  hipMemsetAsync(cnt, 0, 512 * sizeof(int), stream);
  k_convert<<<NB * ND / (256 * 4), 256, 0, stream>>>(
      (const float4*)emb, (ushort4*)ebf, lab, pmKey, nmKey, pSum, nSum, cnt);

  dim3 grid(32, 64);   // 32 col-chunks x 64 row-groups
  k_simpass<0><<<grid, 256, 0, stream>>>(ebf, lab, pmKey, nmKey, pSum, nSum, selfSim);
  k_simpass<1><<<grid, 256, 0, stream>>>(ebf, lab, pmKey, nmKey, pSum, nSum, selfSim);
  k_final<<<1, 1024, 0, stream>>>(pmKey, nmKey, pSum, nSum, selfSim, lab, cnt, out);
}